// Round 3
// baseline (254.847 us; speedup 1.0000x reference)
//
#include <hip/hip_runtime.h>

// SubPixelUpscaling (pixel shuffle), r=2.
// in : (B=8, H=256, W=256, Cin=256) f32, NHWC
// out: (B=8, OH=512, OW=512, Cout=64) f32, NHWC
// out[n, 2h+r1, 2w+r2, c] = in[n, h, w, 4c + 2*r1 + r2]
//
// Lane c loads float4 in[pix, 4c..4c+3] (1KB/wave, coalesced). Quad-lane
// 4x4 transpose (shfl_xor 1,2) -> each lane stores ONE float4 of 4
// consecutive output channels; per wave-store: two contiguous 512B runs.
// x4 unroll with batched loads for MLP; non-temporal on both streams
// (touch-once data, skip LLC round-trip).

typedef float f32x4 __attribute__((ext_vector_type(4)));

__global__ __launch_bounds__(256) void SubPixelUpscaling_kernel(
    const float* __restrict__ in, float* __restrict__ out, int total) {
    const int stride  = gridDim.x * blockDim.x;   // multiple of 64
    const int pixstep = stride >> 6;
    const int tid = blockIdx.x * blockDim.x + threadIdx.x;

    // lane-derived, loop-invariant (stride % 64 == 0)
    const int  c    = tid & 63;
    const bool p1   = (c & 1) != 0;
    const bool p2   = (c & 2) != 0;
    const int  s    = c & 3;
    const int  r1   = s >> 1;
    const int  r2   = s & 1;
    const int  cb   = c & ~3;
    const int  coff = c << 2;

    int t = tid;
    for (; t + 3 * stride < total; t += 4 * stride) {
        const int pix = t >> 6;

        f32x4 v[4];
#pragma unroll
        for (int k = 0; k < 4; ++k) {
            v[k] = __builtin_nontemporal_load(
                reinterpret_cast<const f32x4*>(in + ((pix + k * pixstep) << 8) + coff));
        }

#pragma unroll
        for (int k = 0; k < 4; ++k) {
            const int p = pix + k * pixstep;
            const int w = p & 255;
            const int h = (p >> 8) & 255;
            const int n = p >> 16;

            // 4x4 quad-lane transpose
            float a  = p1 ? v[k][0] : v[k][1];
            float b  = p1 ? v[k][2] : v[k][3];
            float ra = __shfl_xor(a, 1);
            float rb = __shfl_xor(b, 1);
            float u0 = p1 ? ra      : v[k][0];
            float u1 = p1 ? v[k][1] : ra;
            float u2 = p1 ? rb      : v[k][2];
            float u3 = p1 ? v[k][3] : rb;

            float cc = p2 ? u0 : u2;
            float dd = p2 ? u1 : u3;
            float rc = __shfl_xor(cc, 2);
            float rd = __shfl_xor(dd, 2);
            f32x4 wv;
            wv[0] = p2 ? rc : u0;
            wv[1] = p2 ? rd : u1;
            wv[2] = p2 ? u2 : rc;
            wv[3] = p2 ? u3 : rd;

            const int obase = ((((n << 9) + (h << 1) + r1) << 9) | ((w << 1) + r2)) << 6 | cb;
            __builtin_nontemporal_store(wv, reinterpret_cast<f32x4*>(out + obase));
        }
    }
    // tail (not taken for this problem size; kept for safety)
    for (; t < total; t += stride) {
        const int p = t >> 6;
        const int w = p & 255;
        const int h = (p >> 8) & 255;
        const int n = p >> 16;
        f32x4 v = __builtin_nontemporal_load(
            reinterpret_cast<const f32x4*>(in + (p << 8) + coff));

        float a  = p1 ? v[0] : v[1];
        float b  = p1 ? v[2] : v[3];
        float ra = __shfl_xor(a, 1);
        float rb = __shfl_xor(b, 1);
        float u0 = p1 ? ra   : v[0];
        float u1 = p1 ? v[1] : ra;
        float u2 = p1 ? rb   : v[2];
        float u3 = p1 ? v[3] : rb;
        float cc = p2 ? u0 : u2;
        float dd = p2 ? u1 : u3;
        float rc = __shfl_xor(cc, 2);
        float rd = __shfl_xor(dd, 2);
        f32x4 wv;
        wv[0] = p2 ? rc : u0;
        wv[1] = p2 ? rd : u1;
        wv[2] = p2 ? u2 : rc;
        wv[3] = p2 ? u3 : rd;

        const int obase = ((((n << 9) + (h << 1) + r1) << 9) | ((w << 1) + r2)) << 6 | cb;
        __builtin_nontemporal_store(wv, reinterpret_cast<f32x4*>(out + obase));
    }
}

extern "C" void kernel_launch(void* const* d_in, const int* in_sizes, int n_in,
                              void* d_out, int out_size, void* d_ws, size_t ws_size,
                              hipStream_t stream) {
    const float* in = (const float*)d_in[0];
    float* out = (float*)d_out;

    const int total = out_size / 4;  // one thread-iteration per 4 output elements
    const int block = 256;
    const int grid  = 2048;          // 8 blocks/CU -> 32 waves/CU (occupancy cap)

    SubPixelUpscaling_kernel<<<grid, block, 0, stream>>>(in, out, total);
}

// Round 4
// 219.836 us; speedup vs baseline: 1.1593x; 1.1593x over previous
//
#include <hip/hip_runtime.h>

// SubPixelUpscaling (pixel shuffle), r=2.
// in : (B=8, H=256, W=256, Cin=256) f32, NHWC
// out: (B=8, OH=512, OW=512, Cout=64) f32, NHWC
// out[n, 2h+r1, 2w+r2, c] = in[n, h, w, 4c + 2*r1 + r2]
//
// Each wave processes an even input-pixel pair (p, p+1) per iteration:
//   load : 2 x 1KB contiguous (wave-level dwordx4, like a copy kernel)
//   LDS  : redistribute into output order (per-wave buffer, no barrier;
//          8 ds_write_b32 @ 2 lanes/bank = conflict-free, 2 ds_read_b128)
//   store: 2 x 1KB contiguous runs (out rows 2h / 2h+1, pixels 2w..2w+3)
// Every global memory instruction is a full 1KB wave-contiguous run.

typedef float f32x4 __attribute__((ext_vector_type(4)));

__global__ __launch_bounds__(256) void SubPixelUpscaling_kernel(
    const float* __restrict__ in, float* __restrict__ out, int npairs) {
    __shared__ __align__(16) float lds[4][2][256];  // [wave][out-row][4 pix x 64 ch]

    const int lane = threadIdx.x & 63;
    const int wid  = threadIdx.x >> 6;
    const int gw   = blockIdx.x * 4 + wid;  // global wave id (block = 4 waves)
    const int nw   = gridDim.x * 4;

    float* const row0 = &lds[wid][0][0];
    float* const row1 = &lds[wid][1][0];
    const int l4 = lane << 2;

    for (int pair = gw; pair < npairs; pair += nw) {
        const int p = pair << 1;          // even input pixel; pair stays in one row (W=256)
        const int w = p & 255;
        const int h = (p >> 8) & 255;
        const int n = p >> 16;

        // lane c holds input channels 4c..4c+3 = out channel c, subpixels s=0..3
        const f32x4 vA = *reinterpret_cast<const f32x4*>(in + (p << 8) + l4);
        const f32x4 vB = *reinterpret_cast<const f32x4*>(in + ((p + 1) << 8) + l4);

        // row0[pp*64 + c] = out[n, 2h,   2w+pp, c];  row1: 2h+1
        row0[lane]       = vA.x;   // pp=0 <- pixel p,   s=0
        row0[64 + lane]  = vA.y;   // pp=1 <- pixel p,   s=1
        row0[128 + lane] = vB.x;   // pp=2 <- pixel p+1, s=0
        row0[192 + lane] = vB.y;   // pp=3 <- pixel p+1, s=1
        row1[lane]       = vA.z;   // s=2
        row1[64 + lane]  = vA.w;   // s=3
        row1[128 + lane] = vB.z;
        row1[192 + lane] = vB.w;

        asm volatile("s_waitcnt lgkmcnt(0)" ::: "memory");

        const f32x4 r0 = *reinterpret_cast<const f32x4*>(row0 + l4);
        const f32x4 r1 = *reinterpret_cast<const f32x4*>(row1 + l4);

        // out float index of [n, 2h, 2w, 0]; row1 is +512*64 floats
        const int ob = ((((n << 9) + (h << 1)) << 9) + (w << 1)) << 6;
        *reinterpret_cast<f32x4*>(out + ob + l4)         = r0;
        *reinterpret_cast<f32x4*>(out + ob + 32768 + l4) = r1;
    }
}

extern "C" void kernel_launch(void* const* d_in, const int* in_sizes, int n_in,
                              void* d_out, int out_size, void* d_ws, size_t ws_size,
                              hipStream_t stream) {
    const float* in = (const float*)d_in[0];
    float* out = (float*)d_out;

    // input pixels = 8*256*256 = 524288 -> 262144 pairs; 8192 waves -> 32 iters
    const int npairs = (out_size / 4) / 128;  // out_size/256ch.. = B*H*W/2
    const int block = 256;
    const int grid  = 2048;  // 8 blocks/CU, grid-stride

    SubPixelUpscaling_kernel<<<grid, block, 0, stream>>>(in, out, npairs);
}

// Round 5
// 213.747 us; speedup vs baseline: 1.1923x; 1.0285x over previous
//
#include <hip/hip_runtime.h>

// SubPixelUpscaling (pixel shuffle), r=2.
// in : (B=8, H=256, W=256, Cin=256) f32, NHWC
// out: (B=8, OH=512, OW=512, Cout=64) f32, NHWC
// out[n, 2h+r1, 2w+r2, c] = in[n, h, w, 4c + 2*r1 + r2]
//
// R3 structure (per-wave LDS redistribute, all global ops 1KB wave-contiguous)
// + 2-stage software pipeline: next pair's loads are issued BEFORE the LDS/
// store phase of the current pair, keeping reads continuously in flight and
// overlapping HBM read/write streams (avoids bursty turnaround).

typedef float f32x4 __attribute__((ext_vector_type(4)));

__global__ __launch_bounds__(256) void SubPixelUpscaling_kernel(
    const float* __restrict__ in, float* __restrict__ out, int npairs) {
    __shared__ __align__(16) float lds[4][2][256];  // [wave][out-row][4 pix x 64 ch]

    const int lane = threadIdx.x & 63;
    const int wid  = threadIdx.x >> 6;
    const int gw   = blockIdx.x * 4 + wid;  // global wave id (block = 4 waves)
    const int nw   = gridDim.x * 4;

    float* const row0 = &lds[wid][0][0];
    float* const row1 = &lds[wid][1][0];
    const int l4 = lane << 2;
    const float* const inl = in + l4;

    int pair = gw;
    if (pair >= npairs) return;

    // prologue: load current pair
    f32x4 a0 = *reinterpret_cast<const f32x4*>(inl + ((pair << 1) << 8));
    f32x4 a1 = *reinterpret_cast<const f32x4*>(inl + (((pair << 1) + 1) << 8));

    while (true) {
        const int next = pair + nw;           // wave-uniform branch
        f32x4 b0, b1;
        const bool have_next = next < npairs;
        if (have_next) {                      // issue next loads FIRST
            b0 = *reinterpret_cast<const f32x4*>(inl + ((next << 1) << 8));
            b1 = *reinterpret_cast<const f32x4*>(inl + (((next << 1) + 1) << 8));
        }

        // ---- process current pair (a0, a1) ----
        const int p = pair << 1;
        const int w = p & 255;
        const int h = (p >> 8) & 255;
        const int n = p >> 16;

        // row0[pp*64 + c] = out[n, 2h, 2w+pp, c];  row1: 2h+1
        row0[lane]       = a0.x;   // pp=0 <- pixel p,   s=0
        row0[64 + lane]  = a0.y;   // pp=1 <- pixel p,   s=1
        row0[128 + lane] = a1.x;   // pp=2 <- pixel p+1, s=0
        row0[192 + lane] = a1.y;   // pp=3 <- pixel p+1, s=1
        row1[lane]       = a0.z;   // s=2
        row1[64 + lane]  = a0.w;   // s=3
        row1[128 + lane] = a1.z;
        row1[192 + lane] = a1.w;

        asm volatile("s_waitcnt lgkmcnt(0)" ::: "memory");

        const f32x4 r0 = *reinterpret_cast<const f32x4*>(row0 + l4);
        const f32x4 r1 = *reinterpret_cast<const f32x4*>(row1 + l4);

        const int ob = ((((n << 9) + (h << 1)) << 9) + (w << 1)) << 6;
        *reinterpret_cast<f32x4*>(out + ob + l4)         = r0;
        *reinterpret_cast<f32x4*>(out + ob + 32768 + l4) = r1;

        if (!have_next) break;
        a0 = b0;
        a1 = b1;
        pair = next;
    }
}

extern "C" void kernel_launch(void* const* d_in, const int* in_sizes, int n_in,
                              void* d_out, int out_size, void* d_ws, size_t ws_size,
                              hipStream_t stream) {
    const float* in = (const float*)d_in[0];
    float* out = (float*)d_out;

    // input pixels = 8*256*256 = 524288 -> 262144 pairs; 8192 waves -> 32 iters
    const int npairs = (out_size / 4) / 128;
    const int block = 256;
    const int grid  = 2048;  // 8 blocks/CU -> 32 waves/CU

    SubPixelUpscaling_kernel<<<grid, block, 0, stream>>>(in, out, npairs);
}

// Round 6
// 203.546 us; speedup vs baseline: 1.2520x; 1.0501x over previous
//
#include <hip/hip_runtime.h>

// SubPixelUpscaling (pixel shuffle), r=2.
// in : (B=8, H=256, W=256, Cin=256) f32, NHWC
// out: (B=8, OH=512, OW=512, Cout=64) f32, NHWC
// out[n, 2h+r1, 2w+r2, c] = x[n, h, w, 4c + 2*r1 + r2]
//
// R4 structure (per-wave LDS redistribute, all global ops 1KB wave-contiguous,
// 2-stage load pipeline) + NON-TEMPORAL STORES (single variable vs R4):
// the 536MB write stream is touch-once; NT stores skip L2 write-allocate,
// removing dirty-eviction churn between the read-miss and write streams.

typedef float f32x4 __attribute__((ext_vector_type(4)));

__global__ __launch_bounds__(256) void SubPixelUpscaling_kernel(
    const float* __restrict__ in, float* __restrict__ out, int npairs) {
    __shared__ __align__(16) float lds[4][2][256];  // [wave][out-row][4 pix x 64 ch]

    const int lane = threadIdx.x & 63;
    const int wid  = threadIdx.x >> 6;
    const int gw   = blockIdx.x * 4 + wid;  // global wave id (block = 4 waves)
    const int nw   = gridDim.x * 4;

    float* const row0 = &lds[wid][0][0];
    float* const row1 = &lds[wid][1][0];
    const int l4 = lane << 2;
    const float* const inl = in + l4;

    int pair = gw;
    if (pair >= npairs) return;

    // prologue: load current pair
    f32x4 a0 = *reinterpret_cast<const f32x4*>(inl + ((pair << 1) << 8));
    f32x4 a1 = *reinterpret_cast<const f32x4*>(inl + (((pair << 1) + 1) << 8));

    while (true) {
        const int next = pair + nw;           // wave-uniform branch
        f32x4 b0, b1;
        const bool have_next = next < npairs;
        if (have_next) {                      // issue next loads FIRST
            b0 = *reinterpret_cast<const f32x4*>(inl + ((next << 1) << 8));
            b1 = *reinterpret_cast<const f32x4*>(inl + (((next << 1) + 1) << 8));
        }

        // ---- process current pair (a0, a1) ----
        const int p = pair << 1;
        const int w = p & 255;
        const int h = (p >> 8) & 255;
        const int n = p >> 16;

        // row0[pp*64 + c] = out[n, 2h, 2w+pp, c];  row1: 2h+1
        row0[lane]       = a0.x;   // pp=0 <- pixel p,   s=0
        row0[64 + lane]  = a0.y;   // pp=1 <- pixel p,   s=1
        row0[128 + lane] = a1.x;   // pp=2 <- pixel p+1, s=0
        row0[192 + lane] = a1.y;   // pp=3 <- pixel p+1, s=1
        row1[lane]       = a0.z;   // s=2
        row1[64 + lane]  = a0.w;   // s=3
        row1[128 + lane] = a1.z;
        row1[192 + lane] = a1.w;

        asm volatile("s_waitcnt lgkmcnt(0)" ::: "memory");

        const f32x4 r0 = *reinterpret_cast<const f32x4*>(row0 + l4);
        const f32x4 r1 = *reinterpret_cast<const f32x4*>(row1 + l4);

        const int ob = ((((n << 9) + (h << 1)) << 9) + (w << 1)) << 6;
        __builtin_nontemporal_store(r0, reinterpret_cast<f32x4*>(out + ob + l4));
        __builtin_nontemporal_store(r1, reinterpret_cast<f32x4*>(out + ob + 32768 + l4));

        if (!have_next) break;
        a0 = b0;
        a1 = b1;
        pair = next;
    }
}

extern "C" void kernel_launch(void* const* d_in, const int* in_sizes, int n_in,
                              void* d_out, int out_size, void* d_ws, size_t ws_size,
                              hipStream_t stream) {
    const float* in = (const float*)d_in[0];
    float* out = (float*)d_out;

    // input pixels = 8*256*256 = 524288 -> 262144 pairs; 8192 waves -> 32 iters
    const int npairs = (out_size / 4) / 128;
    const int block = 256;
    const int grid  = 2048;  // 8 blocks/CU -> 32 waves/CU

    SubPixelUpscaling_kernel<<<grid, block, 0, stream>>>(in, out, npairs);
}

// Round 7
// 191.142 us; speedup vs baseline: 1.3333x; 1.0649x over previous
//
#include <hip/hip_runtime.h>

// SubPixelUpscaling (pixel shuffle), r=2.
// in : (B=8, H=256, W=256, Cin=256) f32, NHWC
// out: (B=8, OH=512, OW=512, Cout=64) f32, NHWC
// out[n, 2h+r1, 2w+r2, c] = x[n, h, w, 4c + 2*r1 + r2]
//
// R5 structure (per-wave LDS redistribute, all global ops 1KB wave-contiguous,
// 2-stage load pipeline, NT stores) + NON-TEMPORAL LOADS (single variable vs
// R5): the read stream is also touch-once; skip L2 read-allocation churn.

typedef float f32x4 __attribute__((ext_vector_type(4)));

__global__ __launch_bounds__(256) void SubPixelUpscaling_kernel(
    const float* __restrict__ in, float* __restrict__ out, int npairs) {
    __shared__ __align__(16) float lds[4][2][256];  // [wave][out-row][4 pix x 64 ch]

    const int lane = threadIdx.x & 63;
    const int wid  = threadIdx.x >> 6;
    const int gw   = blockIdx.x * 4 + wid;  // global wave id (block = 4 waves)
    const int nw   = gridDim.x * 4;

    float* const row0 = &lds[wid][0][0];
    float* const row1 = &lds[wid][1][0];
    const int l4 = lane << 2;
    const float* const inl = in + l4;

    int pair = gw;
    if (pair >= npairs) return;

    // prologue: load current pair
    f32x4 a0 = __builtin_nontemporal_load(
        reinterpret_cast<const f32x4*>(inl + ((pair << 1) << 8)));
    f32x4 a1 = __builtin_nontemporal_load(
        reinterpret_cast<const f32x4*>(inl + (((pair << 1) + 1) << 8)));

    while (true) {
        const int next = pair + nw;           // wave-uniform branch
        f32x4 b0, b1;
        const bool have_next = next < npairs;
        if (have_next) {                      // issue next loads FIRST
            b0 = __builtin_nontemporal_load(
                reinterpret_cast<const f32x4*>(inl + ((next << 1) << 8)));
            b1 = __builtin_nontemporal_load(
                reinterpret_cast<const f32x4*>(inl + (((next << 1) + 1) << 8)));
        }

        // ---- process current pair (a0, a1) ----
        const int p = pair << 1;
        const int w = p & 255;
        const int h = (p >> 8) & 255;
        const int n = p >> 16;

        // row0[pp*64 + c] = out[n, 2h, 2w+pp, c];  row1: 2h+1
        row0[lane]       = a0.x;   // pp=0 <- pixel p,   s=0
        row0[64 + lane]  = a0.y;   // pp=1 <- pixel p,   s=1
        row0[128 + lane] = a1.x;   // pp=2 <- pixel p+1, s=0
        row0[192 + lane] = a1.y;   // pp=3 <- pixel p+1, s=1
        row1[lane]       = a0.z;   // s=2
        row1[64 + lane]  = a0.w;   // s=3
        row1[128 + lane] = a1.z;
        row1[192 + lane] = a1.w;

        asm volatile("s_waitcnt lgkmcnt(0)" ::: "memory");

        const f32x4 r0 = *reinterpret_cast<const f32x4*>(row0 + l4);
        const f32x4 r1 = *reinterpret_cast<const f32x4*>(row1 + l4);

        const int ob = ((((n << 9) + (h << 1)) << 9) + (w << 1)) << 6;
        __builtin_nontemporal_store(r0, reinterpret_cast<f32x4*>(out + ob + l4));
        __builtin_nontemporal_store(r1, reinterpret_cast<f32x4*>(out + ob + 32768 + l4));

        if (!have_next) break;
        a0 = b0;
        a1 = b1;
        pair = next;
    }
}

extern "C" void kernel_launch(void* const* d_in, const int* in_sizes, int n_in,
                              void* d_out, int out_size, void* d_ws, size_t ws_size,
                              hipStream_t stream) {
    const float* in = (const float*)d_in[0];
    float* out = (float*)d_out;

    // input pixels = 8*256*256 = 524288 -> 262144 pairs; 8192 waves -> 32 iters
    const int npairs = (out_size / 4) / 128;
    const int block = 256;
    const int grid  = 2048;  // 8 blocks/CU -> 32 waves/CU

    SubPixelUpscaling_kernel<<<grid, block, 0, stream>>>(in, out, npairs);
}

// Round 8
// 184.135 us; speedup vs baseline: 1.3840x; 1.0381x over previous
//
#include <hip/hip_runtime.h>

// SubPixelUpscaling (pixel shuffle), r=2.
// in : (B=8, H=256, W=256, Cin=256) f32, NHWC
// out: (B=8, OH=512, OW=512, Cout=64) f32, NHWC
// out[n, 2h+r1, 2w+r2, c] = x[n, h, w, 4c + 2*r1 + r2]
//
// R6 structure (per-wave LDS redistribute, NT loads+stores, 2-stage load
// pipeline) at 2x granularity: 4 input pixels (one aligned quad) per
// wave-iteration. Loads: 4 x 1KB contiguous in flight; stores: 2 x 2KB
// contiguous runs (out rows 2h/2h+1, pixels 2w..2w+7). Half the iterations.

typedef float f32x4 __attribute__((ext_vector_type(4)));

__global__ __launch_bounds__(256) void SubPixelUpscaling_kernel(
    const float* __restrict__ in, float* __restrict__ out, int nquads) {
    __shared__ __align__(16) float lds[4][2][512];  // [wave][out-row][8 pix x 64 ch]

    const int lane = threadIdx.x & 63;
    const int wid  = threadIdx.x >> 6;
    const int gw   = blockIdx.x * 4 + wid;  // global wave id (block = 4 waves)
    const int nw   = gridDim.x * 4;

    float* const row0 = &lds[wid][0][0];
    float* const row1 = &lds[wid][1][0];
    const int l4 = lane << 2;
    const float* const inl = in + l4;

    int q = gw;
    if (q >= nquads) return;

    // prologue: load current quad (pixels 4q..4q+3; W=256 so same image row)
    f32x4 a0 = __builtin_nontemporal_load(reinterpret_cast<const f32x4*>(inl + ((q << 2) << 8)));
    f32x4 a1 = __builtin_nontemporal_load(reinterpret_cast<const f32x4*>(inl + (((q << 2) + 1) << 8)));
    f32x4 a2 = __builtin_nontemporal_load(reinterpret_cast<const f32x4*>(inl + (((q << 2) + 2) << 8)));
    f32x4 a3 = __builtin_nontemporal_load(reinterpret_cast<const f32x4*>(inl + (((q << 2) + 3) << 8)));

    while (true) {
        const int next = q + nw;              // wave-uniform branch
        f32x4 b0, b1, b2, b3;
        const bool have_next = next < nquads;
        if (have_next) {                      // issue next loads FIRST
            b0 = __builtin_nontemporal_load(reinterpret_cast<const f32x4*>(inl + ((next << 2) << 8)));
            b1 = __builtin_nontemporal_load(reinterpret_cast<const f32x4*>(inl + (((next << 2) + 1) << 8)));
            b2 = __builtin_nontemporal_load(reinterpret_cast<const f32x4*>(inl + (((next << 2) + 2) << 8)));
            b3 = __builtin_nontemporal_load(reinterpret_cast<const f32x4*>(inl + (((next << 2) + 3) << 8)));
        }

        // ---- process current quad ----
        const int p = q << 2;
        const int w = p & 255;
        const int h = (p >> 8) & 255;
        const int n = p >> 16;

        // row0[pp*64 + c] = out[n, 2h, 2w+pp, c] = in[p + (pp>>1)][4c + (pp&1)]
        row0[lane]       = a0.x;  row0[64  + lane] = a0.y;
        row0[128 + lane] = a1.x;  row0[192 + lane] = a1.y;
        row0[256 + lane] = a2.x;  row0[320 + lane] = a2.y;
        row0[384 + lane] = a3.x;  row0[448 + lane] = a3.y;
        // row1: r1=1 -> s in {2,3} -> components z/w
        row1[lane]       = a0.z;  row1[64  + lane] = a0.w;
        row1[128 + lane] = a1.z;  row1[192 + lane] = a1.w;
        row1[256 + lane] = a2.z;  row1[320 + lane] = a2.w;
        row1[384 + lane] = a3.z;  row1[448 + lane] = a3.w;

        asm volatile("s_waitcnt lgkmcnt(0)" ::: "memory");

        const f32x4 r0a = *reinterpret_cast<const f32x4*>(row0 + l4);
        const f32x4 r0b = *reinterpret_cast<const f32x4*>(row0 + 256 + l4);
        const f32x4 r1a = *reinterpret_cast<const f32x4*>(row1 + l4);
        const f32x4 r1b = *reinterpret_cast<const f32x4*>(row1 + 256 + l4);

        // out float index of [n, 2h, 2w, 0]; row 2h+1 is +512*64 floats
        const int ob = ((((n << 9) + (h << 1)) << 9) + (w << 1)) << 6;
        __builtin_nontemporal_store(r0a, reinterpret_cast<f32x4*>(out + ob + l4));
        __builtin_nontemporal_store(r0b, reinterpret_cast<f32x4*>(out + ob + 256 + l4));
        __builtin_nontemporal_store(r1a, reinterpret_cast<f32x4*>(out + ob + 32768 + l4));
        __builtin_nontemporal_store(r1b, reinterpret_cast<f32x4*>(out + ob + 32768 + 256 + l4));

        if (!have_next) break;
        a0 = b0; a1 = b1; a2 = b2; a3 = b3;
        q = next;
    }
}

extern "C" void kernel_launch(void* const* d_in, const int* in_sizes, int n_in,
                              void* d_out, int out_size, void* d_ws, size_t ws_size,
                              hipStream_t stream) {
    const float* in = (const float*)d_in[0];
    float* out = (float*)d_out;

    // input pixels = 8*256*256 = 524288 -> 131072 quads; 8192 waves -> 16 iters
    const int nquads = (out_size / 4) / 256;
    const int block = 256;
    const int grid  = 2048;  // 8 blocks/CU -> 32 waves/CU

    SubPixelUpscaling_kernel<<<grid, block, 0, stream>>>(in, out, nquads);
}

// Round 9
// 184.096 us; speedup vs baseline: 1.3843x; 1.0002x over previous
//
#include <hip/hip_runtime.h>

// SubPixelUpscaling (pixel shuffle), r=2.
// in : (B=8, H=256, W=256, Cin=256) f32, NHWC
// out: (B=8, OH=512, OW=512, Cout=64) f32, NHWC
// out[n, 2h+r1, 2w+r2, c] = x[n, h, w, 4c + 2*r1 + r2]
//
// R7 structure (per-wave LDS redistribute, NT loads+stores, 2-stage load
// pipeline) at octet granularity: 8 input pixels per wave-iteration, split
// into TWO LDS phases reusing the same 16KB/block buffer (no LDS growth).
// Loads: 8 x 1KB contiguous in flight; stores: per output row, phase A+B
// form a 4KB address-sequential run issued back-to-back.

typedef float f32x4 __attribute__((ext_vector_type(4)));

__global__ __launch_bounds__(256) void SubPixelUpscaling_kernel(
    const float* __restrict__ in, float* __restrict__ out, int nocts) {
    __shared__ __align__(16) float lds[4][2][512];  // [wave][out-row][8 pix x 64 ch]

    const int lane = threadIdx.x & 63;
    const int wid  = threadIdx.x >> 6;
    const int gw   = blockIdx.x * 4 + wid;  // global wave id (block = 4 waves)
    const int nw   = gridDim.x * 4;

    float* const row0 = &lds[wid][0][0];
    float* const row1 = &lds[wid][1][0];
    const int l4 = lane << 2;
    const float* const inl = in + l4;

    int o = gw;
    if (o >= nocts) return;

    f32x4 a[8];
#pragma unroll
    for (int j = 0; j < 8; ++j)
        a[j] = __builtin_nontemporal_load(
            reinterpret_cast<const f32x4*>(inl + (((o << 3) + j) << 8)));

    while (true) {
        const int next = o + nw;              // wave-uniform branch
        const bool have_next = next < nocts;
        f32x4 b[8];
        if (have_next) {
#pragma unroll
            for (int j = 0; j < 8; ++j)
                b[j] = __builtin_nontemporal_load(
                    reinterpret_cast<const f32x4*>(inl + (((next << 3) + j) << 8)));
        }

        const int p = o << 3;                 // octet-aligned: same image row
        const int w = p & 255;
        const int h = (p >> 8) & 255;
        const int n = p >> 16;
        // out float index of [n, 2h, 2w, 0]; row 2h+1 is +512*64 floats
        const int ob = ((((n << 9) + (h << 1)) << 9) + (w << 1)) << 6;

        // ---- phase A: input pixels p..p+3 -> output pixels 2w..2w+7 ----
        row0[lane]       = a[0].x;  row0[64  + lane] = a[0].y;
        row0[128 + lane] = a[1].x;  row0[192 + lane] = a[1].y;
        row0[256 + lane] = a[2].x;  row0[320 + lane] = a[2].y;
        row0[384 + lane] = a[3].x;  row0[448 + lane] = a[3].y;
        row1[lane]       = a[0].z;  row1[64  + lane] = a[0].w;
        row1[128 + lane] = a[1].z;  row1[192 + lane] = a[1].w;
        row1[256 + lane] = a[2].z;  row1[320 + lane] = a[2].w;
        row1[384 + lane] = a[3].z;  row1[448 + lane] = a[3].w;

        asm volatile("s_waitcnt lgkmcnt(0)" ::: "memory");

        {
            const f32x4 r0a = *reinterpret_cast<const f32x4*>(row0 + l4);
            const f32x4 r0b = *reinterpret_cast<const f32x4*>(row0 + 256 + l4);
            const f32x4 r1a = *reinterpret_cast<const f32x4*>(row1 + l4);
            const f32x4 r1b = *reinterpret_cast<const f32x4*>(row1 + 256 + l4);
            __builtin_nontemporal_store(r0a, reinterpret_cast<f32x4*>(out + ob + l4));
            __builtin_nontemporal_store(r0b, reinterpret_cast<f32x4*>(out + ob + 256 + l4));
            __builtin_nontemporal_store(r1a, reinterpret_cast<f32x4*>(out + ob + 32768 + l4));
            __builtin_nontemporal_store(r1b, reinterpret_cast<f32x4*>(out + ob + 32768 + 256 + l4));
        }

        // ---- phase B: input pixels p+4..p+7 -> output pixels 2w+8..2w+15 ----
        // same-wave DS ops execute in order: WAR reuse of the buffer is safe.
        asm volatile("" ::: "memory");
        row0[lane]       = a[4].x;  row0[64  + lane] = a[4].y;
        row0[128 + lane] = a[5].x;  row0[192 + lane] = a[5].y;
        row0[256 + lane] = a[6].x;  row0[320 + lane] = a[6].y;
        row0[384 + lane] = a[7].x;  row0[448 + lane] = a[7].y;
        row1[lane]       = a[4].z;  row1[64  + lane] = a[4].w;
        row1[128 + lane] = a[5].z;  row1[192 + lane] = a[5].w;
        row1[256 + lane] = a[6].z;  row1[320 + lane] = a[6].w;
        row1[384 + lane] = a[7].z;  row1[448 + lane] = a[7].w;

        asm volatile("s_waitcnt lgkmcnt(0)" ::: "memory");

        {
            const f32x4 r0a = *reinterpret_cast<const f32x4*>(row0 + l4);
            const f32x4 r0b = *reinterpret_cast<const f32x4*>(row0 + 256 + l4);
            const f32x4 r1a = *reinterpret_cast<const f32x4*>(row1 + l4);
            const f32x4 r1b = *reinterpret_cast<const f32x4*>(row1 + 256 + l4);
            __builtin_nontemporal_store(r0a, reinterpret_cast<f32x4*>(out + ob + 512 + l4));
            __builtin_nontemporal_store(r0b, reinterpret_cast<f32x4*>(out + ob + 768 + l4));
            __builtin_nontemporal_store(r1a, reinterpret_cast<f32x4*>(out + ob + 32768 + 512 + l4));
            __builtin_nontemporal_store(r1b, reinterpret_cast<f32x4*>(out + ob + 32768 + 768 + l4));
        }

        if (!have_next) break;
#pragma unroll
        for (int j = 0; j < 8; ++j) a[j] = b[j];
        o = next;
    }
}

extern "C" void kernel_launch(void* const* d_in, const int* in_sizes, int n_in,
                              void* d_out, int out_size, void* d_ws, size_t ws_size,
                              hipStream_t stream) {
    const float* in = (const float*)d_in[0];
    float* out = (float*)d_out;

    // input pixels = 8*256*256 = 524288 -> 65536 octets; 8192 waves -> 8 iters
    const int nocts = (out_size / 4) / 512;
    const int block = 256;
    const int grid  = 2048;  // 8 blocks/CU (LDS 16KB/block allows 10)

    SubPixelUpscaling_kernel<<<grid, block, 0, stream>>>(in, out, nocts);
}